// Round 1
// baseline (232.064 us; speedup 1.0000x reference)
//
#include <hip/hip_runtime.h>
#include <hip/hip_bf16.h>
#include <cstdint>
#include <cstddef>

// MyBaseRNN: out[t,b,h] = tanh( sum_i x[t,b,i]*W[h,i] + input_bias[h]
//                               + sum_j h0[b,j]*U[h,j] + hidden_bias[h] )
// hidden = out[T-1]
// GEMM: M=131072 (t*64+b), N=512 (h), K=512 (i). A=x row-major MxK,
// B=W row-major NxK (i.e. already "B^T" layout) -> m97-style gemm_bt.

#define T_LEN 2048
#define BATCH 64
#define ISZ 512
#define HSZ 512
#define MTOT (T_LEN * BATCH) /* 131072 */

#define BM 128
#define BN 128
#define BK 64

typedef __attribute__((ext_vector_type(8))) __bf16 bf16x8;
typedef __attribute__((ext_vector_type(4))) __bf16 bf16x4;
typedef __attribute__((ext_vector_type(4))) float f32x4;

#define GLOBAL_AS __attribute__((address_space(1)))
#define LDS_AS __attribute__((address_space(3)))

__device__ __forceinline__ float fast_tanh(float v) {
    // tanh(v) = 1 - 2/(exp(2v)+1); branch-free, handles +-inf saturation.
    float e = __expf(2.0f * v);
    return 1.0f - 2.0f / (e + 1.0f);
}

// ---------- Kernel 1: W (fp32, HxI row-major) -> bf16 ----------
__global__ __launch_bounds__(256) void convw_kernel(const float* __restrict__ W,
                                                    __bf16* __restrict__ Wbf) {
    int i = blockIdx.x * 256 + threadIdx.x; // one float4 per thread, 65536 total
    f32x4 f = ((const f32x4*)W)[i];
    bf16x4 v;
    v[0] = (__bf16)f[0]; v[1] = (__bf16)f[1];
    v[2] = (__bf16)f[2]; v[3] = (__bf16)f[3];
    ((bf16x4*)Wbf)[i] = v;
}

// ---------- Kernel 2: uh[b][h] = h0[b,:]·U[h,:] + hb[h] + ib[h] (fp32) ----------
__global__ __launch_bounds__(512) void uh_kernel(const float* __restrict__ prev,
                                                 const float* __restrict__ U,
                                                 const float* __restrict__ hb,
                                                 const float* __restrict__ ib,
                                                 float* __restrict__ uh) {
    __shared__ float sp[HSZ];
    int b = blockIdx.x, h = threadIdx.x;
    sp[h] = prev[b * HSZ + h];
    __syncthreads();
    const float* urow = U + (size_t)h * HSZ;
    float acc = 0.f;
#pragma unroll 4
    for (int i = 0; i < HSZ; i += 4) {
        f32x4 u4 = *(const f32x4*)(urow + i);
        acc += u4[0] * sp[i] + u4[1] * sp[i + 1] + u4[2] * sp[i + 2] + u4[3] * sp[i + 3];
    }
    uh[b * HSZ + h] = acc + hb[h] + ib[h];
}

// ---------- Kernel 3: main GEMM + bias + tanh ----------
// 128x128 tile, BK=64, 4 waves (2x2), acc 4x4 frags of 16x16x32 bf16 MFMA.
// A staged via reg (fp32->bf16 convert), B staged via global_load_lds (16B).
__global__ __launch_bounds__(256, 2) void gemm_tanh_kernel(
        const float* __restrict__ x, const __bf16* __restrict__ Wbf,
        const float* __restrict__ uh, float* __restrict__ out) {
    __shared__ __attribute__((aligned(16))) __bf16 sA[BM * BK];
    __shared__ __attribute__((aligned(16))) __bf16 sB[BN * BK];

    // XCD-bijective swizzle: nwg=4096 (%8==0). XCD x gets m-panels
    // [x*128, (x+1)*128), each panel's 4 n-tiles consecutive -> A-panel L2 reuse.
    int orig = blockIdx.x;
    int wg = (orig & 7) * 512 + (orig >> 3);
    int mt = wg >> 2, nt = wg & 3;

    int tid = threadIdx.x;
    int lane = tid & 63, wid = tid >> 6;
    int wr = wid >> 1, wc = wid & 1;
    int l15 = lane & 15, l4 = lane >> 4;

    f32x4 acc[4][4] = {};

    const size_t m0 = (size_t)mt * BM;
    const int n0 = nt * BN;

#pragma unroll 1
    for (int ks = 0; ks < ISZ; ks += BK) {
        // ---- stage A: 128x64 fp32 -> bf16 LDS (row-major [128][64]) ----
        // 1024 pairs of float4; p -> row=p>>3, pc=p&7 (8 pairs = 64 floats/row)
#pragma unroll
        for (int it = 0; it < 4; ++it) {
            int p = it * 256 + tid;
            int row = p >> 3, pc = p & 7;
            const float* src = x + (m0 + row) * ISZ + ks + pc * 8;
            f32x4 f0 = *(const f32x4*)src;
            f32x4 f1 = *(const f32x4*)(src + 4);
            bf16x8 v;
            v[0] = (__bf16)f0[0]; v[1] = (__bf16)f0[1];
            v[2] = (__bf16)f0[2]; v[3] = (__bf16)f0[3];
            v[4] = (__bf16)f1[0]; v[5] = (__bf16)f1[1];
            v[6] = (__bf16)f1[2]; v[7] = (__bf16)f1[3];
            *(bf16x8*)&sA[row * BK + pc * 8] = v;
        }
        // ---- stage B: 128x64 bf16 via global_load_lds width-16 ----
#pragma unroll
        for (int j = 0; j < 4; ++j) {
            int chunk = wid * 4 + j;          // 0..15, wave-uniform
            int o = chunk * 1024 + lane * 16; // byte offset in 16KB tile
            int n = o >> 7;                   // 128B per row
            int c = (o & 127) >> 1;           // bf16 col within row
            const __bf16* g = Wbf + (size_t)(n0 + n) * ISZ + ks + c;
            __builtin_amdgcn_global_load_lds((const GLOBAL_AS uint32_t*)g,
                                             (LDS_AS uint32_t*)((char*)sB + chunk * 1024),
                                             16, 0, 0);
        }
        __syncthreads();
        // ---- compute: 2 k-chunks of 32, 16 MFMA each ----
#pragma unroll
        for (int kk = 0; kk < 2; ++kk) {
            bf16x8 af[4], bfr[4];
#pragma unroll
            for (int mi = 0; mi < 4; ++mi)
                af[mi] = *(const bf16x8*)&sA[(wr * 64 + mi * 16 + l15) * BK + kk * 32 + l4 * 8];
#pragma unroll
            for (int ni = 0; ni < 4; ++ni)
                bfr[ni] = *(const bf16x8*)&sB[(wc * 64 + ni * 16 + l15) * BK + kk * 32 + l4 * 8];
#pragma unroll
            for (int mi = 0; mi < 4; ++mi)
#pragma unroll
                for (int ni = 0; ni < 4; ++ni)
                    acc[mi][ni] = __builtin_amdgcn_mfma_f32_16x16x32_bf16(
                        af[mi], bfr[ni], acc[mi][ni], 0, 0, 0);
        }
        __syncthreads();
    }

    // ---- epilogue: + uh, tanh, store ----
    // C/D layout (m89-verified): col = lane&15, row = (lane>>4)*4 + reg
#pragma unroll
    for (int mi = 0; mi < 4; ++mi) {
#pragma unroll
        for (int ni = 0; ni < 4; ++ni) {
#pragma unroll
            for (int r = 0; r < 4; ++r) {
                int ml = wr * 64 + mi * 16 + l4 * 4 + r;
                size_t m = m0 + ml;
                int n = n0 + wc * 64 + ni * 16 + l15;
                float v = acc[mi][ni][r] + uh[(ml & 63) * HSZ + n];
                out[m * HSZ + n] = fast_tanh(v);
            }
        }
    }
}

// ---------- Kernel 4: hidden = outputs[T-1] ----------
__global__ __launch_bounds__(256) void copyh_kernel(const float* __restrict__ out,
                                                    float* __restrict__ hid) {
    int i = blockIdx.x * 256 + threadIdx.x; // 32768 elems
    hid[i] = out[(size_t)(MTOT - BATCH) * HSZ + i];
}

extern "C" void kernel_launch(void* const* d_in, const int* in_sizes, int n_in,
                              void* d_out, int out_size, void* d_ws, size_t ws_size,
                              hipStream_t stream) {
    const float* x  = (const float*)d_in[0];
    const float* ph = (const float*)d_in[1];
    const float* W  = (const float*)d_in[2];
    const float* U  = (const float*)d_in[3];
    const float* hb = (const float*)d_in[4];
    const float* ib = (const float*)d_in[5];
    float* out = (float*)d_out;

    __bf16* Wbf = (__bf16*)d_ws;                        // 512 KB
    float* uh   = (float*)((char*)d_ws + 512 * 1024);   // 128 KB

    hipLaunchKernelGGL(convw_kernel, dim3(256), dim3(256), 0, stream, W, Wbf);
    hipLaunchKernelGGL(uh_kernel, dim3(64), dim3(512), 0, stream, ph, U, hb, ib, uh);
    hipLaunchKernelGGL(gemm_tanh_kernel, dim3(4096), dim3(256), 0, stream, x, Wbf, uh, out);
    hipLaunchKernelGGL(copyh_kernel, dim3(128), dim3(256), 0, stream,
                       out, out + (size_t)MTOT * HSZ);
}